// Round 2
// baseline (4358.471 us; speedup 1.0000x reference)
//
#include <hip/hip_runtime.h>
#include <math.h>

namespace {

constexpr int T  = 4096;
constexpr int NB = 256;   // batch
constexpr int I  = 64;
constexpr int H  = 256;
constexpr int O  = 64;
constexpr int HP = 288;   // padded h buffer: addr(k) = k + (k>>5)*4

// 512 threads/block, one block per batch row. One barrier per time step.
// Stage A (h update): thread owns j in {jx, jx+128}, k in [q*64, q*64+64).
// Stage B (y proj, deferred 1 step): thread owns output o, k in [seg*32,+32).
__global__ __launch_bounds__(512, 2) void rnn_fused(
    const float* __restrict__ xin,   // [T,NB,I]
    const float* __restrict__ Wih,   // [H,I]
    const float* __restrict__ Whh,   // [H,H]
    const float* __restrict__ Who,   // [O,H]
    float* __restrict__ out)         // [T*NB*O] ++ [NB*H]
{
  const int b   = blockIdx.x;
  const int tid = threadIdx.x;
  const int jx  = tid >> 2;   // 0..127
  const int q   = tid & 3;    // k-quarter
  const int o   = tid >> 3;   // 0..63
  const int seg = tid & 7;    // k-slice for y

  __shared__ __align__(16) float hbuf[2][HP];
  __shared__ __align__(16) float x_s[2][I];

  // ---- resident weights (192 floats/thread) ----
  float whh[2][64];
#pragma unroll
  for (int jj = 0; jj < 2; ++jj) {
    const float* r = Whh + (size_t)(jx + jj * 128) * H + q * 64;
#pragma unroll
    for (int c = 0; c < 16; ++c) {
      float4 v = *reinterpret_cast<const float4*>(r + c * 4);
      whh[jj][c*4+0] = v.x; whh[jj][c*4+1] = v.y;
      whh[jj][c*4+2] = v.z; whh[jj][c*4+3] = v.w;
    }
  }
  float wih[2][16];
#pragma unroll
  for (int jj = 0; jj < 2; ++jj) {
    const float* r = Wih + (size_t)(jx + jj * 128) * I + q * 16;
#pragma unroll
    for (int c = 0; c < 4; ++c) {
      float4 v = *reinterpret_cast<const float4*>(r + c * 4);
      wih[jj][c*4+0] = v.x; wih[jj][c*4+1] = v.y;
      wih[jj][c*4+2] = v.z; wih[jj][c*4+3] = v.w;
    }
  }
  float who[32];
  {
    const float* r = Who + (size_t)o * H + seg * 32;
#pragma unroll
    for (int c = 0; c < 8; ++c) {
      float4 v = *reinterpret_cast<const float4*>(r + c * 4);
      who[c*4+0] = v.x; who[c*4+1] = v.y; who[c*4+2] = v.z; who[c*4+3] = v.w;
    }
  }

  // ---- init: h(-1)=0, x(0) staged ----
  if (tid < HP) hbuf[0][tid] = 0.f;
  if (tid < 16) {
    float4 v = *reinterpret_cast<const float4*>(xin + (size_t)b * I + tid * 4);
    *reinterpret_cast<float4*>(&x_s[0][tid * 4]) = v;
  }
  __syncthreads();

  const int wj = jx + ((jx >> 5) << 2);   // padded addr of jx
  int p = 0;                              // hbuf[p] holds h(t-1) at loop top

  for (int t = 0; t < T; ++t) {
    // ---- deferred stage B: y(t-1) = h(t-1) @ Who^T ----
    if (t > 0) {
      const float* hb2 = &hbuf[p][seg * 36];   // padded addr of seg*32
      float y0 = 0.f, y1 = 0.f;
#pragma unroll
      for (int c = 0; c < 8; ++c) {
        float4 v = *reinterpret_cast<const float4*>(hb2 + c * 4);
        if (c & 1) {
          y1 = fmaf(v.x, who[c*4+0], y1); y1 = fmaf(v.y, who[c*4+1], y1);
          y1 = fmaf(v.z, who[c*4+2], y1); y1 = fmaf(v.w, who[c*4+3], y1);
        } else {
          y0 = fmaf(v.x, who[c*4+0], y0); y0 = fmaf(v.y, who[c*4+1], y0);
          y0 = fmaf(v.z, who[c*4+2], y0); y0 = fmaf(v.w, who[c*4+3], y0);
        }
      }
      float y = y0 + y1;
      y += __shfl_xor(y, 1);
      y += __shfl_xor(y, 2);
      y += __shfl_xor(y, 4);
      if (seg == 0) out[((size_t)(t - 1) * NB + b) * O + o] = y;
    }

    // ---- x prefetch for t+1 ----
    float4 xpre;
    const bool pre = (t + 1 < T) && (tid < 16);
    if (pre)
      xpre = *reinterpret_cast<const float4*>(xin + ((size_t)(t + 1) * NB + b) * I + tid * 4);

    // ---- stage A: h(t) = tanh(x(t)@Wih^T + h(t-1)@Whh^T) ----
    const float* hb = &hbuf[p][q * 72];      // padded addr of q*64
    const float* xb = &x_s[t & 1][q * 16];
    float a0 = 0.f, a1 = 0.f, a2 = 0.f, a3 = 0.f;
#pragma unroll
    for (int c = 0; c < 16; ++c) {
      const int m = c * 4;
      float4 hv = *reinterpret_cast<const float4*>(hb + m + ((m >= 32) ? 4 : 0));
      if (c & 1) {
        a1 = fmaf(hv.x, whh[0][m+0], a1); a1 = fmaf(hv.y, whh[0][m+1], a1);
        a1 = fmaf(hv.z, whh[0][m+2], a1); a1 = fmaf(hv.w, whh[0][m+3], a1);
        a3 = fmaf(hv.x, whh[1][m+0], a3); a3 = fmaf(hv.y, whh[1][m+1], a3);
        a3 = fmaf(hv.z, whh[1][m+2], a3); a3 = fmaf(hv.w, whh[1][m+3], a3);
      } else {
        a0 = fmaf(hv.x, whh[0][m+0], a0); a0 = fmaf(hv.y, whh[0][m+1], a0);
        a0 = fmaf(hv.z, whh[0][m+2], a0); a0 = fmaf(hv.w, whh[0][m+3], a0);
        a2 = fmaf(hv.x, whh[1][m+0], a2); a2 = fmaf(hv.y, whh[1][m+1], a2);
        a2 = fmaf(hv.z, whh[1][m+2], a2); a2 = fmaf(hv.w, whh[1][m+3], a2);
      }
    }
#pragma unroll
    for (int c = 0; c < 4; ++c) {
      float4 xv = *reinterpret_cast<const float4*>(xb + c * 4);
      a0 = fmaf(xv.x, wih[0][c*4+0], a0); a0 = fmaf(xv.y, wih[0][c*4+1], a0);
      a0 = fmaf(xv.z, wih[0][c*4+2], a0); a0 = fmaf(xv.w, wih[0][c*4+3], a0);
      a2 = fmaf(xv.x, wih[1][c*4+0], a2); a2 = fmaf(xv.y, wih[1][c*4+1], a2);
      a2 = fmaf(xv.z, wih[1][c*4+2], a2); a2 = fmaf(xv.w, wih[1][c*4+3], a2);
    }
    float s0 = a0 + a1, s1 = a2 + a3;
    s0 += __shfl_xor(s0, 1); s0 += __shfl_xor(s0, 2);
    s1 += __shfl_xor(s1, 1); s1 += __shfl_xor(s1, 2);

    s0 = fminf(fmaxf(s0, -15.f), 15.f);
    s1 = fminf(fmaxf(s1, -15.f), 15.f);
    const float e0 = __expf(2.f * s0);
    const float e1 = __expf(2.f * s1);
    const float h0 = 1.f - 2.f / (e0 + 1.f);
    const float h1 = 1.f - 2.f / (e1 + 1.f);

    float* hw = &hbuf[p ^ 1][0];
    if (q == 0)      hw[wj]       = h0;
    else if (q == 1) hw[wj + 144] = h1;   // padded addr of jx+128

    if (pre) *reinterpret_cast<float4*>(&x_s[(t + 1) & 1][tid * 4]) = xpre;

    __syncthreads();
    p ^= 1;
  }

  // ---- tail: y(T-1) + h_last ----
  {
    const float* hb2 = &hbuf[p][seg * 36];
    float y0 = 0.f, y1 = 0.f;
#pragma unroll
    for (int c = 0; c < 8; ++c) {
      float4 v = *reinterpret_cast<const float4*>(hb2 + c * 4);
      if (c & 1) {
        y1 = fmaf(v.x, who[c*4+0], y1); y1 = fmaf(v.y, who[c*4+1], y1);
        y1 = fmaf(v.z, who[c*4+2], y1); y1 = fmaf(v.w, who[c*4+3], y1);
      } else {
        y0 = fmaf(v.x, who[c*4+0], y0); y0 = fmaf(v.y, who[c*4+1], y0);
        y0 = fmaf(v.z, who[c*4+2], y0); y0 = fmaf(v.w, who[c*4+3], y0);
      }
    }
    float y = y0 + y1;
    y += __shfl_xor(y, 1);
    y += __shfl_xor(y, 2);
    y += __shfl_xor(y, 4);
    if (seg == 0) out[((size_t)(T - 1) * NB + b) * O + o] = y;
  }
  if (tid < H)
    out[(size_t)T * NB * O + (size_t)b * H + tid] = hbuf[p][tid + ((tid >> 5) << 2)];
}

}  // namespace

extern "C" void kernel_launch(void* const* d_in, const int* in_sizes, int n_in,
                              void* d_out, int out_size, void* d_ws, size_t ws_size,
                              hipStream_t stream) {
  const float* xin = (const float*)d_in[0];
  const float* Wih = (const float*)d_in[1];
  const float* Whh = (const float*)d_in[2];
  const float* Who = (const float*)d_in[3];
  float* out = (float*)d_out;
  hipLaunchKernelGGL(rnn_fused, dim3(NB), dim3(512), 0, stream,
                     xin, Wih, Whh, Who, out);
}